// Round 1
// baseline (428.077 us; speedup 1.0000x reference)
//
#include <hip/hip_runtime.h>
#include <stdint.h>

// Problem constants (setup_inputs: T=4096, B=4096, C=2)
#define T_STEPS 4096
#define B_SIZE  4096
#define NWORDS  (T_STEPS / 32)   // 128 packed words of 32 timesteps each

// BETA_MEM = 0.9, BETA_INH = 0.6, THRESHOLD = 1.0
// Reference step (per batch element b):
//   cur_exc = x0*w00 + x1*w01
//   inh     = 0.6*inh + x0
//   cur_inh = w_inh * inh
//   cur     = cur_exc + cur_inh
//   reset   = (mem > 1)           // spike_fn(mem - 1): equivalent for f32
//   mem     = (0.9*mem + cur) - reset
//   spk     = (mem > 1)
// Outputs: spk_rec, exc_rec(=cur_exc), inh_rec(=cur_inh), mem_rec, each (T,B).

// ---------------------------------------------------------------------------
// K0: pack spike bits. x is (T,B,2) f32 with values exactly 0.0 or 1.0.
// p0[i*B+b] holds bit k = (x[(32i+k), b, 0] != 0); p1 likewise for channel 1.
// ---------------------------------------------------------------------------
__global__ __launch_bounds__(256) void k_pack(const float2* __restrict__ x,
                                              uint32_t* __restrict__ p0,
                                              uint32_t* __restrict__ p1) {
    uint32_t gid = blockIdx.x * 256u + threadIdx.x;
    uint32_t i = gid >> 12;              // word index (B_SIZE == 4096)
    uint32_t b = gid & (B_SIZE - 1);     // batch index -> coalesced across lanes
    const float2* xp = x + (size_t)i * 32u * B_SIZE + b;
    uint32_t b0 = 0u, b1 = 0u;
#pragma unroll
    for (int k = 0; k < 32; ++k) {
        float2 v = xp[(size_t)k * B_SIZE];
        b0 |= (v.x != 0.0f ? 1u : 0u) << k;
        b1 |= (v.y != 0.0f ? 1u : 0u) << k;
    }
    p0[(size_t)i * B_SIZE + b] = b0;
    p1[(size_t)i * B_SIZE + b] = b1;
}

// ---------------------------------------------------------------------------
// K1: serial scan over T per batch element, from packed bits (4 MiB, cached).
// Writes exact state checkpoints (mem, inh) BEFORE each 32-step word.
// ---------------------------------------------------------------------------
__global__ __launch_bounds__(256) void k_scan(const uint32_t* __restrict__ p0,
                                              const uint32_t* __restrict__ p1,
                                              const float* __restrict__ w_exc,
                                              const float* __restrict__ w_inh_p,
                                              float* __restrict__ mem_ck,
                                              float* __restrict__ inh_ck) {
    int b = blockIdx.x * 256 + threadIdx.x;
    const float w00 = w_exc[0], w01 = w_exc[1], winh = w_inh_p[0];
    float mem = 0.0f, inh = 0.0f;

    if (w00 == 0.0f && winh == 0.0f) {
        // Fast path: cur = w01*x1 exactly; inh does not affect mem.
        uint32_t w1 = p1[b];
        for (int i = 0; i < NWORDS; ++i) {
            uint32_t w1n = (i + 1 < NWORDS) ? p1[(size_t)(i + 1) * B_SIZE + b] : 0u;
            mem_ck[(size_t)i * B_SIZE + b] = mem;
#pragma unroll
            for (int k = 0; k < 32; ++k) {
                float x1f = (float)((w1 >> k) & 1u);
                float r   = (mem > 1.0f) ? 1.0f : 0.0f;  // old-mem reset (parallel to mul)
                float m1  = __fmul_rn(0.9f, mem);
                // x1f*w01 is exact (x in {0,1}), so this fma == round(m1 + cur).
                float m2  = __fmaf_rn(x1f, w01, m1);
                mem       = __fsub_rn(m2, r);
            }
            w1 = w1n;
        }
    } else {
        uint32_t w0 = p0[b], w1 = p1[b];
        for (int i = 0; i < NWORDS; ++i) {
            uint32_t w0n = (i + 1 < NWORDS) ? p0[(size_t)(i + 1) * B_SIZE + b] : 0u;
            uint32_t w1n = (i + 1 < NWORDS) ? p1[(size_t)(i + 1) * B_SIZE + b] : 0u;
            mem_ck[(size_t)i * B_SIZE + b] = mem;
            inh_ck[(size_t)i * B_SIZE + b] = inh;
#pragma unroll
            for (int k = 0; k < 32; ++k) {
                float x0f = (float)((w0 >> k) & 1u);
                float x1f = (float)((w1 >> k) & 1u);
                float exc = __fadd_rn(__fmul_rn(x0f, w00), __fmul_rn(x1f, w01));
                inh       = __fadd_rn(__fmul_rn(0.6f, inh), x0f);
                float ci  = __fmul_rn(winh, inh);
                float cur = __fadd_rn(exc, ci);
                float r   = (mem > 1.0f) ? 1.0f : 0.0f;
                float m1  = __fmul_rn(0.9f, mem);
                float m2  = __fadd_rn(m1, cur);
                mem       = __fsub_rn(m2, r);
            }
            w0 = w0n; w1 = w1n;
        }
    }
}

// ---------------------------------------------------------------------------
// K2: parallel replay. One thread per (32-step chunk, batch element); starts
// from the exact checkpoint and writes all 4 output records, coalesced.
// ---------------------------------------------------------------------------
__global__ __launch_bounds__(256) void k_replay(const uint32_t* __restrict__ p0,
                                                const uint32_t* __restrict__ p1,
                                                const float* __restrict__ w_exc,
                                                const float* __restrict__ w_inh_p,
                                                const float* __restrict__ mem_ck,
                                                const float* __restrict__ inh_ck,
                                                float* __restrict__ out) {
    uint32_t gid = blockIdx.x * 256u + threadIdx.x;
    uint32_t i = gid >> 12;
    uint32_t b = gid & (B_SIZE - 1);
    float* __restrict__ spk_o = out;
    float* __restrict__ exc_o = out + (size_t)T_STEPS * B_SIZE;
    float* __restrict__ inh_o = out + 2 * (size_t)T_STEPS * B_SIZE;
    float* __restrict__ mem_o = out + 3 * (size_t)T_STEPS * B_SIZE;
    const float w00 = w_exc[0], w01 = w_exc[1], winh = w_inh_p[0];
    float mem = mem_ck[(size_t)i * B_SIZE + b];
    size_t base = (size_t)i * 32u * B_SIZE + b;

    if (w00 == 0.0f && winh == 0.0f) {
        uint32_t w1 = p1[(size_t)i * B_SIZE + b];
#pragma unroll
        for (int k = 0; k < 32; ++k) {
            float x1f = (float)((w1 >> k) & 1u);
            float exc = __fmul_rn(x1f, w01);              // == cur_exc exactly
            float r   = (mem > 1.0f) ? 1.0f : 0.0f;
            float m1  = __fmul_rn(0.9f, mem);
            float m2  = __fmaf_rn(x1f, w01, m1);          // identical rounding to add
            mem       = __fsub_rn(m2, r);
            float spk = (mem > 1.0f) ? 1.0f : 0.0f;
            size_t idx = base + (size_t)k * B_SIZE;
            spk_o[idx] = spk;
            exc_o[idx] = exc;
            inh_o[idx] = 0.0f;                            // w_inh * inh == +0
            mem_o[idx] = mem;
        }
    } else {
        float inh = inh_ck[(size_t)i * B_SIZE + b];
        uint32_t w0 = p0[(size_t)i * B_SIZE + b];
        uint32_t w1 = p1[(size_t)i * B_SIZE + b];
#pragma unroll
        for (int k = 0; k < 32; ++k) {
            float x0f = (float)((w0 >> k) & 1u);
            float x1f = (float)((w1 >> k) & 1u);
            float exc = __fadd_rn(__fmul_rn(x0f, w00), __fmul_rn(x1f, w01));
            inh       = __fadd_rn(__fmul_rn(0.6f, inh), x0f);
            float ci  = __fmul_rn(winh, inh);
            float cur = __fadd_rn(exc, ci);
            float r   = (mem > 1.0f) ? 1.0f : 0.0f;
            float m1  = __fmul_rn(0.9f, mem);
            float m2  = __fadd_rn(m1, cur);
            mem       = __fsub_rn(m2, r);
            float spk = (mem > 1.0f) ? 1.0f : 0.0f;
            size_t idx = base + (size_t)k * B_SIZE;
            spk_o[idx] = spk;
            exc_o[idx] = exc;
            inh_o[idx] = ci;
            mem_o[idx] = mem;
        }
    }
}

// ---------------------------------------------------------------------------
// Fallback: fully serial per batch element, reads floats directly. Only used
// if the workspace is too small for the pipeline (correctness safety net).
// ---------------------------------------------------------------------------
__global__ __launch_bounds__(256) void k_naive(const float2* __restrict__ x,
                                               const float* __restrict__ w_exc,
                                               const float* __restrict__ w_inh_p,
                                               float* __restrict__ out) {
    int b = blockIdx.x * 256 + threadIdx.x;
    const float w00 = w_exc[0], w01 = w_exc[1], winh = w_inh_p[0];
    float* __restrict__ spk_o = out;
    float* __restrict__ exc_o = out + (size_t)T_STEPS * B_SIZE;
    float* __restrict__ inh_o = out + 2 * (size_t)T_STEPS * B_SIZE;
    float* __restrict__ mem_o = out + 3 * (size_t)T_STEPS * B_SIZE;
    float mem = 0.0f, inh = 0.0f;
    for (int t = 0; t < T_STEPS; ++t) {
        float2 v = x[(size_t)t * B_SIZE + b];
        float exc = __fadd_rn(__fmul_rn(v.x, w00), __fmul_rn(v.y, w01));
        inh       = __fadd_rn(__fmul_rn(0.6f, inh), v.x);
        float ci  = __fmul_rn(winh, inh);
        float cur = __fadd_rn(exc, ci);
        float r   = (mem > 1.0f) ? 1.0f : 0.0f;
        float m1  = __fmul_rn(0.9f, mem);
        float m2  = __fadd_rn(m1, cur);
        mem       = __fsub_rn(m2, r);
        float spk = (mem > 1.0f) ? 1.0f : 0.0f;
        size_t idx = (size_t)t * B_SIZE + b;
        spk_o[idx] = spk;
        exc_o[idx] = exc;
        inh_o[idx] = ci;
        mem_o[idx] = mem;
    }
}

extern "C" void kernel_launch(void* const* d_in, const int* in_sizes, int n_in,
                              void* d_out, int out_size, void* d_ws, size_t ws_size,
                              hipStream_t stream) {
    const float2* x      = (const float2*)d_in[0];  // (T,B,2) f32
    const float*  w_exc  = (const float*)d_in[1];   // (1,2) f32
    const float*  w_inh  = (const float*)d_in[2];   // scalar f32
    float* out = (float*)d_out;

    const size_t nw = (size_t)NWORDS * B_SIZE;
    const size_t need = nw * (sizeof(uint32_t) * 2 + sizeof(float) * 2); // 8 MiB

    if (ws_size >= need) {
        uint32_t* p0     = (uint32_t*)d_ws;
        uint32_t* p1     = p0 + nw;
        float*    mem_ck = (float*)(p1 + nw);
        float*    inh_ck = mem_ck + nw;

        // K0: pack (T/32 * B threads)
        k_pack<<<(NWORDS * B_SIZE) / 256, 256, 0, stream>>>(x, p0, p1);
        // K1: serial checkpoint scan (B threads)
        k_scan<<<B_SIZE / 256, 256, 0, stream>>>(p0, p1, w_exc, w_inh, mem_ck, inh_ck);
        // K2: parallel replay + output (T/32 * B threads)
        k_replay<<<(NWORDS * B_SIZE) / 256, 256, 0, stream>>>(p0, p1, w_exc, w_inh,
                                                              mem_ck, inh_ck, out);
    } else {
        k_naive<<<B_SIZE / 256, 256, 0, stream>>>(x, w_exc, w_inh, out);
    }
}